// Round 3
// baseline (442.916 us; speedup 1.0000x reference)
//
#include <hip/hip_runtime.h>

// Sliding-window CMVN, window K=301, reflect padding.
// feats: [B=64, T=8192, C=80] fp32 -> out same shape.
//
// One thread per (batch, 4-channel group, time-chunk of G=64).
// Lane loads float4 (16 B) over 4 adjacent channels -> coalescing sweet spot.
// Running window sums S[4], Q[4] stream along t:
//   window for output t = [t-150, t+150]; slide adds t+151, drops t-150.
// Init: 301-element window sum per thread, amortized over G outputs
// (re-reads are L2/L3 hits; input 168 MB < 256 MB L3).
//
// Grid: 320 thr/block (5 waves; 16 slots x 20 float4-columns), 512 blocks
// = 2 blocks/CU, 10 waves/CU. Memory-bound: 336 MB HBM -> ~53 us floor.

namespace {
constexpr int K   = 301;
constexpr int PAD = 150;          // K/2
constexpr float EPS = 1e-8f;
constexpr int Bb = 64;
constexpr int T  = 8192;
constexpr int C  = 80;
constexpr int C4 = C / 4;         // 20 float4 columns
constexpr int G  = 64;            // outputs (time steps) per thread
constexpr int NCHUNK = T / G;     // 128
constexpr int THREADS = 320;
}

__global__ __launch_bounds__(THREADS)
void cmvn_stream4(const float* __restrict__ in, float* __restrict__ out) {
    const int g  = blockIdx.x * THREADS + threadIdx.x;
    const int c4 = g % C4;
    const int rc = g / C4;                // chunk + NCHUNK * b
    const int chunk = rc % NCHUNK;
    const int b     = rc / NCHUNK;

    const float* __restrict__ row  = in  + (size_t)b * T * C + c4 * 4;
    float* __restrict__       orow = out + (size_t)b * T * C + c4 * 4;

    const int t0 = chunk * G;

    auto ld4 = [&](int t) -> float4 {
        return *reinterpret_cast<const float4*>(row + (size_t)t * C);
    };

    // ---- init: window sums for output t0: u in [t0-PAD, t0+PAD] ----
    float S0 = 0.f, S1 = 0.f, S2 = 0.f, S3 = 0.f;
    float Q0 = 0.f, Q1 = 0.f, Q2 = 0.f, Q3 = 0.f;
    #pragma unroll 4
    for (int u = t0 - PAD; u <= t0 + PAD; ++u) {
        int ru = u;
        if (ru < 0)  ru = -ru;                 // reflect low
        if (ru >= T) ru = 2 * (T - 1) - ru;    // reflect high
        const float4 v = ld4(ru);
        S0 += v.x; S1 += v.y; S2 += v.z; S3 += v.w;
        Q0 = fmaf(v.x, v.x, Q0); Q1 = fmaf(v.y, v.y, Q1);
        Q2 = fmaf(v.z, v.z, Q2); Q3 = fmaf(v.w, v.w, Q3);
    }

    constexpr float inv_k = 1.0f / (float)K;

    // ---- stream G outputs ----
    #pragma unroll 4
    for (int i = 0; i < G; ++i) {
        const int t = t0 + i;
        const float4 x = ld4(t);

        float4 o;
        {
            const float mu = S0 * inv_k;
            float var = fmaxf(fmaf(Q0, inv_k, -(mu * mu)), EPS);
            o.x = (x.x - mu) * rsqrtf(var);
        }
        {
            const float mu = S1 * inv_k;
            float var = fmaxf(fmaf(Q1, inv_k, -(mu * mu)), EPS);
            o.y = (x.y - mu) * rsqrtf(var);
        }
        {
            const float mu = S2 * inv_k;
            float var = fmaxf(fmaf(Q2, inv_k, -(mu * mu)), EPS);
            o.z = (x.z - mu) * rsqrtf(var);
        }
        {
            const float mu = S3 * inv_k;
            float var = fmaxf(fmaf(Q3, inv_k, -(mu * mu)), EPS);
            o.w = (x.w - mu) * rsqrtf(var);
        }
        *reinterpret_cast<float4*>(orow + (size_t)t * C) = o;

        // slide: add x[t+PAD+1] (only high reflect), drop x[t-PAD] (only low)
        const int ul = t + PAD + 1;
        const int ut = t - PAD;
        const int rl = (ul >= T) ? (2 * (T - 1) - ul) : ul;
        const int rt = (ut < 0) ? -ut : ut;
        const float4 xl = ld4(rl);
        const float4 xt = ld4(rt);
        // off-chain deltas -> loop-carried chain = one add per accumulator
        S0 += xl.x - xt.x; S1 += xl.y - xt.y;
        S2 += xl.z - xt.z; S3 += xl.w - xt.w;
        Q0 += fmaf(xl.x, xl.x, -(xt.x * xt.x));
        Q1 += fmaf(xl.y, xl.y, -(xt.y * xt.y));
        Q2 += fmaf(xl.z, xl.z, -(xt.z * xt.z));
        Q3 += fmaf(xl.w, xl.w, -(xt.w * xt.w));
    }
}

extern "C" void kernel_launch(void* const* d_in, const int* in_sizes, int n_in,
                              void* d_out, int out_size, void* d_ws, size_t ws_size,
                              hipStream_t stream) {
    const float* in = (const float*)d_in[0];
    float* out = (float*)d_out;
    constexpr int total  = Bb * NCHUNK * C4;  // 163,840 threads
    constexpr int blocks = total / THREADS;   // 512 -> exactly 2 blocks/CU
    cmvn_stream4<<<blocks, THREADS, 0, stream>>>(in, out);
}

// Round 5
// 430.893 us; speedup vs baseline: 1.0279x; 1.0279x over previous
//
#include <hip/hip_runtime.h>

// Sliding-window CMVN, K=301, reflect pad. feats [64,8192,80] fp32.
//
// R3 redesign from measured counters (245us, 42% BW, 27% occ, 638MB fetch):
//  - G=32 outputs/thread -> 20 waves/CU (was 10) for latency hiding.
//  - Cooperative init: block computes 32-wide segment sums (S, Q) in LDS;
//    each thread's 301-window init = 8 LDS seg sums + 45 edge elems
//    (was 301 global reads). Issued traffic 1.29 GB -> ~0.95 GB.
//  - Non-temporal stores (via ext_vector f32x4 - HIP float4 class rejected
//    by the builtin): keep L2 for the 3 read streams.
// Block: 640 thr = 32 slots x 20 float4-columns, covers 1024 time steps.

typedef float f32x4 __attribute__((ext_vector_type(4)));

namespace {
constexpr int K   = 301;
constexpr int PAD = 150;
constexpr float EPS = 1e-8f;
constexpr int Bb = 64;
constexpr int T  = 8192;
constexpr int C  = 80;
constexpr int C4 = 20;                 // float4 columns
constexpr int G  = 32;                 // outputs per thread
constexpr int SLOTS = 32;              // time sub-chunks per block
constexpr int THREADS = SLOTS * C4;    // 640 (10 waves)
constexpr int SUPER = SLOTS * G;       // 1024 steps per block
constexpr int NSUPER = T / SUPER;      // 8
constexpr int NSEG = SLOTS + 8;        // 40 segs; absolute seg = j-4
constexpr float INVK = 1.0f / (float)K;
}

__device__ __forceinline__ int reflect(int u) {
    u = (u < 0) ? -u : u;
    return (u >= T) ? (2 * (T - 1) - u) : u;
}

__global__ __launch_bounds__(THREADS, 5)
void cmvn_coop(const float* __restrict__ in, float* __restrict__ out) {
    __shared__ f32x4 segS[NSEG * C4];
    __shared__ f32x4 segQ[NSEG * C4];

    const int tid = threadIdx.x;
    const int bid = blockIdx.x;
    const int sc  = bid % NSUPER;
    const int b   = bid / NSUPER;
    const int B0  = sc * SUPER;
    const float* __restrict__ base_in = in + (size_t)b * T * C;

    // ---- phase 1: 32-wide segment sums for segs j=0..39 (abs j-4) ----
    for (int task = tid; task < NSEG * C4; task += THREADS) {
        const int j  = task / C4;
        const int cc = task % C4;
        const float* __restrict__ r = base_in + cc * 4;
        const int s0 = B0 + (j - 4) * G;
        f32x4 s = {0.f,0.f,0.f,0.f}, q = {0.f,0.f,0.f,0.f};
        #pragma unroll 8
        for (int k = 0; k < G; ++k) {
            const int u = reflect(s0 + k);
            const f32x4 v = *reinterpret_cast<const f32x4*>(r + (size_t)u * C);
            s += v;
            q.x = fmaf(v.x, v.x, q.x); q.y = fmaf(v.y, v.y, q.y);
            q.z = fmaf(v.z, v.z, q.z); q.w = fmaf(v.w, v.w, q.w);
        }
        segS[task] = s;
        segQ[task] = q;
    }
    __syncthreads();

    // ---- phase 2: per-thread init of window sums at t0 ----
    const int c4   = tid % C4;
    const int slot = tid / C4;
    const int t0   = B0 + slot * G;
    const float* __restrict__ row  = base_in + c4 * 4;
    float* __restrict__       orow = out + (size_t)b * T * C + c4 * 4;

    f32x4 S = {0.f,0.f,0.f,0.f}, Q = {0.f,0.f,0.f,0.f};

    const bool interior = (t0 >= PAD) && (t0 + PAD <= T - 1);
    if (interior) {
        // full segs cover [t0-128, t0+127] = abs segs slot-4..slot+3 = j slot..slot+7
        #pragma unroll
        for (int jj = 0; jj < 8; ++jj) {
            S += segS[(slot + jj) * C4 + c4];
            Q += segQ[(slot + jj) * C4 + c4];
        }
        // tail partial [t0-150, t0-129] (22) + head partial [t0+128, t0+150] (23)
        #pragma unroll 4
        for (int u = t0 - PAD; u <= t0 - 129; ++u) {
            const f32x4 v = *reinterpret_cast<const f32x4*>(row + (size_t)u * C);
            S += v;
            Q.x = fmaf(v.x, v.x, Q.x); Q.y = fmaf(v.y, v.y, Q.y);
            Q.z = fmaf(v.z, v.z, Q.z); Q.w = fmaf(v.w, v.w, Q.w);
        }
        #pragma unroll 4
        for (int u = t0 + 128; u <= t0 + PAD; ++u) {
            const f32x4 v = *reinterpret_cast<const f32x4*>(row + (size_t)u * C);
            S += v;
            Q.x = fmaf(v.x, v.x, Q.x); Q.y = fmaf(v.y, v.y, Q.y);
            Q.z = fmaf(v.z, v.z, Q.z); Q.w = fmaf(v.w, v.w, Q.w);
        }
    } else {
        // edge slow path (~3.5% of threads): naive reflect init
        for (int u = t0 - PAD; u <= t0 + PAD; ++u) {
            const int ru = reflect(u);
            const f32x4 v = *reinterpret_cast<const f32x4*>(row + (size_t)ru * C);
            S += v;
            Q.x = fmaf(v.x, v.x, Q.x); Q.y = fmaf(v.y, v.y, Q.y);
            Q.z = fmaf(v.z, v.z, Q.z); Q.w = fmaf(v.w, v.w, Q.w);
        }
    }

    // ---- phase 3: stream G outputs ----
    #pragma unroll 4
    for (int i = 0; i < G; ++i) {
        const int t = t0 + i;
        const f32x4 x = *reinterpret_cast<const f32x4*>(row + (size_t)t * C);

        f32x4 o;
        {
            const float mu = S.x * INVK;
            const float var = fmaxf(fmaf(Q.x, INVK, -(mu * mu)), EPS);
            o.x = (x.x - mu) * rsqrtf(var);
        }
        {
            const float mu = S.y * INVK;
            const float var = fmaxf(fmaf(Q.y, INVK, -(mu * mu)), EPS);
            o.y = (x.y - mu) * rsqrtf(var);
        }
        {
            const float mu = S.z * INVK;
            const float var = fmaxf(fmaf(Q.z, INVK, -(mu * mu)), EPS);
            o.z = (x.z - mu) * rsqrtf(var);
        }
        {
            const float mu = S.w * INVK;
            const float var = fmaxf(fmaf(Q.w, INVK, -(mu * mu)), EPS);
            o.w = (x.w - mu) * rsqrtf(var);
        }
        __builtin_nontemporal_store(o, reinterpret_cast<f32x4*>(orow + (size_t)t * C));

        // slide: add t+151 (high reflect only), drop t-150 (low reflect only)
        const int ul = t + PAD + 1;
        const int ut = t - PAD;
        const int rl = (ul >= T) ? (2 * (T - 1) - ul) : ul;
        const int rt = (ut < 0) ? -ut : ut;
        const f32x4 xl = *reinterpret_cast<const f32x4*>(row + (size_t)rl * C);
        const f32x4 xt = *reinterpret_cast<const f32x4*>(row + (size_t)rt * C);
        S += xl - xt;
        Q.x += fmaf(xl.x, xl.x, -(xt.x * xt.x));
        Q.y += fmaf(xl.y, xl.y, -(xt.y * xt.y));
        Q.z += fmaf(xl.z, xl.z, -(xt.z * xt.z));
        Q.w += fmaf(xl.w, xl.w, -(xt.w * xt.w));
    }
}

extern "C" void kernel_launch(void* const* d_in, const int* in_sizes, int n_in,
                              void* d_out, int out_size, void* d_ws, size_t ws_size,
                              hipStream_t stream) {
    const float* in = (const float*)d_in[0];
    float* out = (float*)d_out;
    constexpr int blocks = Bb * NSUPER;   // 512 -> 2 blocks/CU, 20 waves/CU
    cmvn_coop<<<blocks, THREADS, 0, stream>>>(in, out);
}